// Round 24
// baseline (61.178 us; speedup 1.0000x reference)
//
#include <hip/hip_runtime.h>
#include <hip/hip_bf16.h>

#define NPIX 9216      // H*W
#define NB 2
#define NC 64
#define JBA 48         // 192-j blocks per (b,ic) in attn  (grid = 768 = 3/CU exact)

typedef __attribute__((ext_vector_type(4))) short s16x4;
typedef __attribute__((ext_vector_type(8))) short s16x8;
typedef __attribute__((ext_vector_type(2))) float f32x2;
typedef __attribute__((ext_vector_type(4))) float fp32x4;
typedef __attribute__((ext_vector_type(16))) float f32x16;

#define LOG2E 1.44269504088896340736f

__device__ __forceinline__ float exp2fast(float x) {
#if defined(__has_builtin) && __has_builtin(__builtin_amdgcn_exp2f)
  return __builtin_amdgcn_exp2f(x);
#else
  float r; asm("v_exp_f32 %0, %1" : "=v"(r) : "v"(x)); return r;
#endif
}
#define EXP2(x) exp2fast(x)

__device__ __forceinline__ short bf16b(float f) {
  unsigned u = __builtin_bit_cast(unsigned, f);
  u += 0x7FFFu + ((u >> 16) & 1u);          // RNE, no NaN in this data
  return (short)(u >> 16);
}

__device__ __forceinline__ unsigned cvtpk(float a, float b) {
  unsigned r;
  asm("v_cvt_pk_bf16_f32 %0, %1, %2" : "=v"(r) : "v"(a), "v"(b));
  return r;
}

// Direct global->LDS DMA, 16B per lane. lds base must be wave-uniform.
__device__ __forceinline__ void gload_lds16(const void* g, void* l) {
  __builtin_amdgcn_global_load_lds(
      (const __attribute__((address_space(1))) unsigned*)g,
      (__attribute__((address_space(3))) unsigned*)l, 16, 0, 0);
}

// ---------------- Stage 1 (r18, frozen): thin conv blocks + 2-stage pipeline.
// Grid (288 pixel-tiles, 6 groups, NB), block = 64 threads = 1 wave.
// Groups: 0-3 = v ch 16g..16g+15 (from rv); 4 = q (8 ch, from bev, xLOG2E
// post-loop); 5 = k (8 ch, from rv). Thread = one pixel; x via ping-pong
// xa/xb so chunk c+1 loads hide under chunk c's FMA burst. Weights are
// wave-uniform scalar loads. v-groups: 2KB LDS transpose into the verified
// vbf layout: vbf[b][blk][ks2][s2][c64][t8], i = 32blk+16ks+4s+(t&3)+8(t>>2).
__global__ __launch_bounds__(64, 4) void cvt_qkv_kernel(
    const float* __restrict__ rv, const float* __restrict__ bev,
    const float* __restrict__ Wq, const float* __restrict__ bq,
    const float* __restrict__ Wk, const float* __restrict__ bk,
    const float* __restrict__ Wv, const float* __restrict__ bv,
    short* __restrict__ qbf, short* __restrict__ kbf, short* __restrict__ vbf)
{
  __shared__ short lds[16][66];   // v transpose buffer [ch-in-group][pixel]
  const int tile = blockIdx.x, g = blockIdx.y, b = blockIdx.z;
  const int lane = threadIdx.x;   // 0..63 = pixel within tile
  const int j = tile * 64 + lane;

  const float* xin = ((g == 4) ? bev : rv) + (size_t)b * NC * NPIX + j;

  float xa[8], xb[8];
#pragma unroll
  for (int t = 0; t < 8; ++t) xa[t] = xin[(size_t)t * NPIX];

  if (g < 4) {
    const int g16 = g * 16;
    float acc[16];
#pragma unroll
    for (int u = 0; u < 16; ++u) acc[u] = bv[g16 + u];
#pragma unroll
    for (int cc = 0; cc < 64; cc += 16) {
#pragma unroll
      for (int t = 0; t < 8; ++t) xb[t] = xin[(size_t)(cc + 8 + t) * NPIX];
#pragma unroll
      for (int u = 0; u < 16; ++u) {
#pragma unroll
        for (int t = 0; t < 8; ++t)
          acc[u] = fmaf(Wv[(g16 + u) * 64 + cc + t], xa[t], acc[u]);
      }
      if (cc + 16 < 64) {
#pragma unroll
        for (int t = 0; t < 8; ++t) xa[t] = xin[(size_t)(cc + 16 + t) * NPIX];
      }
#pragma unroll
      for (int u = 0; u < 16; ++u) {
#pragma unroll
        for (int t = 0; t < 8; ++t)
          acc[u] = fmaf(Wv[(g16 + u) * 64 + cc + 8 + t], xb[t], acc[u]);
      }
    }
#pragma unroll
    for (int u = 0; u < 16; ++u) lds[u][lane] = bf16b(acc[u]);
    __syncthreads();
    s16x8* vout = (s16x8*)vbf + (size_t)b * 288 * 256;
#pragma unroll
    for (int r = 0; r < 2; ++r) {
      const int v = r * 64 + lane;          // 0..127
      const int blk_l = v >> 6, ks = (v >> 5) & 1, s = (v >> 4) & 1, c = v & 15;
      s16x8 vv;
#pragma unroll
      for (int t = 0; t < 8; ++t)
        vv[t] = lds[c][blk_l * 32 + ks * 16 + s * 4 + (t & 3) + 8 * (t >> 2)];
      vout[((size_t)(tile * 2 + blk_l)) * 256 + (ks * 2 + s) * 64 + g16 + c] = vv;
    }
  } else {
    const float* W = (g == 4) ? Wq : Wk;
    const float* bias = (g == 4) ? bq : bk;
    float acc[8];
#pragma unroll
    for (int u = 0; u < 8; ++u) acc[u] = bias[u];
#pragma unroll
    for (int cc = 0; cc < 64; cc += 16) {
#pragma unroll
      for (int t = 0; t < 8; ++t) xb[t] = xin[(size_t)(cc + 8 + t) * NPIX];
#pragma unroll
      for (int u = 0; u < 8; ++u) {
#pragma unroll
        for (int t = 0; t < 8; ++t)
          acc[u] = fmaf(W[u * 64 + cc + t], xa[t], acc[u]);
      }
      if (cc + 16 < 64) {
#pragma unroll
        for (int t = 0; t < 8; ++t) xa[t] = xin[(size_t)(cc + 16 + t) * NPIX];
      }
#pragma unroll
      for (int u = 0; u < 8; ++u) {
#pragma unroll
        for (int t = 0; t < 8; ++t)
          acc[u] = fmaf(W[u * 64 + cc + 8 + t], xb[t], acc[u]);
      }
    }
    if (g == 4) {
#pragma unroll
      for (int u = 0; u < 8; ++u) acc[u] *= LOG2E;
    }
    s16x8 p;
#pragma unroll
    for (int u = 0; u < 8; ++u) p[u] = bf16b(acc[u]);
    short* dst = (g == 4) ? qbf : kbf;
    ((s16x8*)dst)[(size_t)b * NPIX + j] = p;
  }
}

// ---------------- Stage 2: flash attention, 32x32x16.  (r13 body; r23:
// 6-wave blocks x 192 j, JBA=48 -> grid 768 = EXACTLY 3 blocks/CU, removing
// the 2-vs-3 block quantization tail of the 576-block grid. Compute body,
// chunking (NCH=9 x 128 i), LDS layout and den path byte-identical.)
// Wave owns ONE 32-j tile (jbase = jb*192 + wid*32), full 64-c accumulation.
// V + q staged via global_load_lds (wave w takes V-slots {w, w+6, w+12<16}),
// double buffered, one barrier per chunk; all 6 waves share the staged V.
// numws (bf16 pairs, native fragment layout, verified r10):
//   addr = ((icb*48+jb)*6+wid)*1024 + u*64 + lane  (uint)
//   with jj=j&31: u = (jj>>3)*2 + ((jj>>1)&1) + 8*(c>>5);
//   lane = ((jj>>2)&1)*32 + (c&31); pair = (j even -> lo16, j odd -> hi16).
template <int NCH>   // NCH = number of 128-i chunks per ic
__global__ __launch_bounds__(384) void attn_kernel(
    const short* __restrict__ qbf, const short* __restrict__ kbf,
    const short* __restrict__ vbf,
    unsigned* __restrict__ numws, float* __restrict__ denws)
{
  __shared__ s16x8 lv[2][1024];   // 32 KB: per chunk 4 units x [ks2][s2][c64]
  __shared__ s16x8 lq[2][128];    // 4 KB: 128 q rows (16B each)

  const int bid = blockIdx.x;
  const int jb = bid % JBA;
  const int rest = bid / JBA;
  const int b = rest % NB;
  const int ic = rest / NB;
  const int tid = threadIdx.x;        // 0..383
  const int wid = tid >> 6, lane = tid & 63;   // wid 0..5
  const int l31 = lane & 31, hi = lane >> 5;
  const int jbase = jb * 192 + wid * 32;
  const int ibase = ic * (NCH * 128);

  const s16x8* q8 = (const s16x8*)qbf + (size_t)b * NPIX;
  const short* krow = kbf + (size_t)b * NPIX * 8;
  const s16x8* v8 = (const s16x8*)vbf + (size_t)b * 288 * 256;

  const f32x16 z16 = {0.f};

  // Score B-operand (wave-fixed): lane (j=l31, s=hi): elems 0-3 =
  // k[jbase+l31][4hi..4hi+3], elems 4-7 = ZERO (k>=8 of the K=16 MFMA).
  s16x8 kf;
  {
    const s16x4 ka = *(const s16x4*)(krow + (size_t)(jbase + l31) * 8 + hi * 4);
    kf[0] = ka[0]; kf[1] = ka[1]; kf[2] = ka[2]; kf[3] = ka[3];
    kf[4] = 0; kf[5] = 0; kf[6] = 0; kf[7] = 0;
  }

  f32x16 acc0 = z16, acc1 = z16;
  f32x2 dA = {0.f, 0.f};
  const int vl = hi * 64 + l31;

  // V chunk = 16 wave-load slots of 64 s16x8 entries each; 6 waves cover
  // {w, w+6, w+12(<16)}. q = 128 rows = 2 slots on waves 0,1.
  auto stage = [&](int ch, int bf) {
    const size_t ebase = ((size_t)(ibase >> 5) + ch * 4) * 256;  // s16x8 entries
    gload_lds16(&v8[ebase + wid * 64 + lane], &lv[bf][wid * 64]);
    gload_lds16(&v8[ebase + (wid + 6) * 64 + lane], &lv[bf][(wid + 6) * 64]);
    if (wid < 4)
      gload_lds16(&v8[ebase + (wid + 12) * 64 + lane], &lv[bf][(wid + 12) * 64]);
    if (wid < 2)
      gload_lds16(&q8[(size_t)ibase + ch * 128 + wid * 64 + lane], &lq[bf][wid * 64]);
  };

  stage(0, 0);
  __syncthreads();           // drains vmcnt(0): buf0 staged

  int buf = 0;
  for (int ch = 0; ch < NCH; ++ch) {
    if (ch + 1 < NCH) stage(ch + 1, buf ^ 1);   // loads fly under compute
#pragma unroll
    for (int u = 0; u < 4; ++u) {
      const s16x4 qh = *(const s16x4*)((const short*)&lq[buf][0] + (u * 32 + l31) * 8 + hi * 4);
      s16x8 af;
      af[0] = qh[0]; af[1] = qh[1]; af[2] = qh[2]; af[3] = qh[3];
      af[4] = 0; af[5] = 0; af[6] = 0; af[7] = 0;
      const s16x8 vf00 = lv[buf][u * 256 + vl];          // ks0, c 0-31
      const s16x8 vf01 = lv[buf][u * 256 + 32 + vl];     // ks0, c 32-63
      const s16x8 vf10 = lv[buf][u * 256 + 128 + vl];    // ks1, c 0-31
      const s16x8 vf11 = lv[buf][u * 256 + 160 + vl];    // ks1, c 32-63

      const f32x16 S = __builtin_amdgcn_mfma_f32_32x32x16_bf16(af, kf, z16, 0, 0, 0);
      const float e0 = EXP2(S[0]),  e1 = EXP2(S[1]),  e2 = EXP2(S[2]),  e3 = EXP2(S[3]);
      const float e4 = EXP2(S[4]),  e5 = EXP2(S[5]),  e6 = EXP2(S[6]),  e7 = EXP2(S[7]);
      const float e8 = EXP2(S[8]),  e9 = EXP2(S[9]),  eA = EXP2(S[10]), eB = EXP2(S[11]);
      const float eC = EXP2(S[12]), eD = EXP2(S[13]), eE = EXP2(S[14]), eF = EXP2(S[15]);
      dA += (f32x2){e0, e1}; dA += (f32x2){e2, e3};
      dA += (f32x2){e4, e5}; dA += (f32x2){e6, e7};
      dA += (f32x2){e8, e9}; dA += (f32x2){eA, eB};
      dA += (f32x2){eC, eD}; dA += (f32x2){eE, eF};
      int4 p0i, p1i;
      p0i.x = cvtpk(e0, e1); p0i.y = cvtpk(e2, e3);
      p0i.z = cvtpk(e4, e5); p0i.w = cvtpk(e6, e7);
      p1i.x = cvtpk(e8, e9); p1i.y = cvtpk(eA, eB);
      p1i.z = cvtpk(eC, eD); p1i.w = cvtpk(eE, eF);
      const s16x8 A0 = __builtin_bit_cast(s16x8, p0i);   // i 0..15 of unit
      const s16x8 A1 = __builtin_bit_cast(s16x8, p1i);   // i 16..31
      acc0 = __builtin_amdgcn_mfma_f32_32x32x16_bf16(A0, vf00, acc0, 0, 0, 0);
      acc1 = __builtin_amdgcn_mfma_f32_32x32x16_bf16(A0, vf01, acc1, 0, 0, 0);
      acc0 = __builtin_amdgcn_mfma_f32_32x32x16_bf16(A1, vf10, acc0, 0, 0, 0);
      acc1 = __builtin_amdgcn_mfma_f32_32x32x16_bf16(A1, vf11, acc1, 0, 0, 0);
    }
    __syncthreads();         // all reads of buf done; next-stage loads drained
    buf ^= 1;
  }

  // den: lanes l and l^32 hold complementary i-subsets of the same j.
  float den = dA[0] + dA[1];
  den += __shfl_xor(den, 32);
  const size_t icb = (size_t)ic * NB + b;
  if (lane < 32) denws[icb * NPIX + jbase + l31] = den;

  // Tail: 16 coalesced uint stores in native fragment layout.
  const size_t wavebase = (((size_t)icb * JBA + jb) * 6 + wid) * 1024;
#pragma unroll
  for (int qd = 0; qd < 4; ++qd) {
    numws[wavebase + (qd * 2 + 0) * 64 + lane] = cvtpk(acc0[4 * qd + 0], acc0[4 * qd + 1]);
    numws[wavebase + (qd * 2 + 1) * 64 + lane] = cvtpk(acc0[4 * qd + 2], acc0[4 * qd + 3]);
    numws[wavebase + (8 + qd * 2 + 0) * 64 + lane] = cvtpk(acc1[4 * qd + 0], acc1[4 * qd + 1]);
    numws[wavebase + (8 + qd * 2 + 1) * 64 + lane] = cvtpk(acc1[4 * qd + 2], acc1[4 * qd + 3]);
  }
}

// ---------------- Stage 3: combine i-splits, normalize, add residual.
// Decode verified in r10 (adapted to JBA=48/6-wave): for output (c, j):
//   jt = j>>5 (32-j tile in [0,288)); jb = jt/6; wid = jt%6; jj = j&31:
//   u = (jj>>3)*2 + ((jj>>1)&1) + 8*(c>>5);
//   lane = ((jj>>2)&1)*32 + (c&31); pair sel = j&1 (even->lo16, odd->hi16).
template <int NIC>
__global__ __launch_bounds__(256) void combine_kernel(
    const float* __restrict__ bev, const unsigned* __restrict__ numws,
    const float* __restrict__ denws, float* __restrict__ out)
{
  const int tid = threadIdx.x;
  const int m = tid & 15;          // j-pair within the 32-j tile: jj = 2m, 2m+1
  const int q = tid >> 4;          // c-quad: c = 4q .. 4q+3
  const int b = blockIdx.y;
  const int j0 = blockIdx.x * 32 + 2 * m;       // even j
  const int jt = j0 >> 5;
  const int jb = jt / 6, wid = jt % 6;
  const int u = (m >> 2) * 2 + (m & 1) + 8 * (q >> 3);
  const int laneoff = ((m >> 1) & 1) * 32 + 4 * (q & 7);

  float n0[4] = {0.f, 0.f, 0.f, 0.f}, n1[4] = {0.f, 0.f, 0.f, 0.f};
  float d0 = 0.f, d1 = 0.f;
#pragma unroll
  for (int ic = 0; ic < NIC; ++ic) {
    const size_t icb = (size_t)ic * NB + b;
    const size_t base = (((icb * JBA + jb) * 6 + wid) * 1024) + u * 64 + laneoff;
    const uint4 un = *(const uint4*)&numws[base];
    n0[0] += __builtin_bit_cast(float, un.x << 16);
    n1[0] += __builtin_bit_cast(float, un.x & 0xFFFF0000u);
    n0[1] += __builtin_bit_cast(float, un.y << 16);
    n1[1] += __builtin_bit_cast(float, un.y & 0xFFFF0000u);
    n0[2] += __builtin_bit_cast(float, un.z << 16);
    n1[2] += __builtin_bit_cast(float, un.z & 0xFFFF0000u);
    n0[3] += __builtin_bit_cast(float, un.w << 16);
    n1[3] += __builtin_bit_cast(float, un.w & 0xFFFF0000u);
    const float2 dd = *(const float2*)&denws[icb * NPIX + j0];
    d0 += dd.x; d1 += dd.y;
  }
  const float r0 = 1.f / d0, r1 = 1.f / d1;
#pragma unroll
  for (int e = 0; e < 4; ++e) {
    const int c = 4 * q + e;
    const size_t o = ((size_t)b * NC + c) * NPIX + j0;
    float2 z2;
    z2.x = bev[o] + n0[e] * r0;
    z2.y = bev[o + 1] + n1[e] * r1;
    *(float2*)&out[o] = z2;
  }
}

extern "C" void kernel_launch(void* const* d_in, const int* in_sizes, int n_in,
                              void* d_out, int out_size, void* d_ws, size_t ws_size,
                              hipStream_t stream) {
  const float* rv  = (const float*)d_in[0];
  const float* bev = (const float*)d_in[1];
  const float* Wq  = (const float*)d_in[2];
  const float* bq  = (const float*)d_in[3];
  const float* Wk  = (const float*)d_in[4];
  const float* bk  = (const float*)d_in[5];
  const float* Wv  = (const float*)d_in[6];
  const float* bv  = (const float*)d_in[7];
  float* out = (float*)d_out;

  short* qbf = (short*)d_ws;
  short* kbf = qbf + (size_t)NB * NPIX * 8;
  short* vbf = kbf + (size_t)NB * NPIX * 8;
  float* denws = (float*)(vbf + (size_t)NB * NPIX * 64);

  const size_t fixed = (size_t)NB * NPIX * (8 + 8 + 64) * 2;  // qkv bytes
  int nic = 8;
  while (nic > 2) {
    size_t need = fixed + (size_t)nic * NB * NPIX * 4                // denws
                        + (size_t)nic * NB * JBA * 6 * 1024 * 4;     // numws
    if (need <= ws_size) break;
    nic >>= 1;
  }
  unsigned* numws = (unsigned*)(denws + (size_t)nic * NB * NPIX);

  cvt_qkv_kernel<<<dim3(288, 6, NB), 64, 0, stream>>>(
      rv, bev, Wq, bq, Wk, bk, Wv, bv, qbf, kbf, vbf);
  const int nblk = nic * NB * JBA;
  if (nic == 8) {
    attn_kernel<9><<<dim3(nblk), 384, 0, stream>>>(qbf, kbf, vbf, numws, denws);
    combine_kernel<8><<<dim3(288, NB), 256, 0, stream>>>(bev, numws, denws, out);
  } else if (nic == 4) {
    attn_kernel<18><<<dim3(nblk), 384, 0, stream>>>(qbf, kbf, vbf, numws, denws);
    combine_kernel<4><<<dim3(288, NB), 256, 0, stream>>>(bev, numws, denws, out);
  } else {
    attn_kernel<36><<<dim3(nblk), 384, 0, stream>>>(qbf, kbf, vbf, numws, denws);
    combine_kernel<2><<<dim3(288, NB), 256, 0, stream>>>(bev, numws, denws, out);
  }
}

// Round 25
// 60.909 us; speedup vs baseline: 1.0044x; 1.0044x over previous
//
#include <hip/hip_runtime.h>
#include <hip/hip_bf16.h>

#define NPIX 9216      // H*W
#define NB 2
#define NC 64
#define JBA 48         // 192-j blocks per (b,ic) in attn  (grid = 768 = 3/CU exact)

typedef __attribute__((ext_vector_type(4))) short s16x4;
typedef __attribute__((ext_vector_type(8))) short s16x8;
typedef __attribute__((ext_vector_type(2))) float f32x2;
typedef __attribute__((ext_vector_type(4))) float fp32x4;
typedef __attribute__((ext_vector_type(16))) float f32x16;

#define LOG2E 1.44269504088896340736f

__device__ __forceinline__ float exp2fast(float x) {
#if defined(__has_builtin) && __has_builtin(__builtin_amdgcn_exp2f)
  return __builtin_amdgcn_exp2f(x);
#else
  float r; asm("v_exp_f32 %0, %1" : "=v"(r) : "v"(x)); return r;
#endif
}
#define EXP2(x) exp2fast(x)

__device__ __forceinline__ short bf16b(float f) {
  unsigned u = __builtin_bit_cast(unsigned, f);
  u += 0x7FFFu + ((u >> 16) & 1u);          // RNE, no NaN in this data
  return (short)(u >> 16);
}

__device__ __forceinline__ unsigned cvtpk(float a, float b) {
  unsigned r;
  asm("v_cvt_pk_bf16_f32 %0, %1, %2" : "=v"(r) : "v"(a), "v"(b));
  return r;
}

// Direct global->LDS DMA, 16B per lane. lds base must be wave-uniform.
__device__ __forceinline__ void gload_lds16(const void* g, void* l) {
  __builtin_amdgcn_global_load_lds(
      (const __attribute__((address_space(1))) unsigned*)g,
      (__attribute__((address_space(3))) unsigned*)l, 16, 0, 0);
}

// ---------------- Stage 1 (r18, frozen): thin conv blocks + 2-stage pipeline.
// Grid (288 pixel-tiles, 6 groups, NB), block = 64 threads = 1 wave.
// Groups: 0-3 = v ch 16g..16g+15 (from rv); 4 = q (8 ch, from bev, xLOG2E
// post-loop); 5 = k (8 ch, from rv). Thread = one pixel; x via ping-pong
// xa/xb so chunk c+1 loads hide under chunk c's FMA burst. Weights are
// wave-uniform scalar loads. v-groups: 2KB LDS transpose into the verified
// vbf layout: vbf[b][blk][ks2][s2][c64][t8], i = 32blk+16ks+4s+(t&3)+8(t>>2).
__global__ __launch_bounds__(64, 4) void cvt_qkv_kernel(
    const float* __restrict__ rv, const float* __restrict__ bev,
    const float* __restrict__ Wq, const float* __restrict__ bq,
    const float* __restrict__ Wk, const float* __restrict__ bk,
    const float* __restrict__ Wv, const float* __restrict__ bv,
    short* __restrict__ qbf, short* __restrict__ kbf, short* __restrict__ vbf)
{
  __shared__ short lds[16][66];   // v transpose buffer [ch-in-group][pixel]
  const int tile = blockIdx.x, g = blockIdx.y, b = blockIdx.z;
  const int lane = threadIdx.x;   // 0..63 = pixel within tile
  const int j = tile * 64 + lane;

  const float* xin = ((g == 4) ? bev : rv) + (size_t)b * NC * NPIX + j;

  float xa[8], xb[8];
#pragma unroll
  for (int t = 0; t < 8; ++t) xa[t] = xin[(size_t)t * NPIX];

  if (g < 4) {
    const int g16 = g * 16;
    float acc[16];
#pragma unroll
    for (int u = 0; u < 16; ++u) acc[u] = bv[g16 + u];
#pragma unroll
    for (int cc = 0; cc < 64; cc += 16) {
#pragma unroll
      for (int t = 0; t < 8; ++t) xb[t] = xin[(size_t)(cc + 8 + t) * NPIX];
#pragma unroll
      for (int u = 0; u < 16; ++u) {
#pragma unroll
        for (int t = 0; t < 8; ++t)
          acc[u] = fmaf(Wv[(g16 + u) * 64 + cc + t], xa[t], acc[u]);
      }
      if (cc + 16 < 64) {
#pragma unroll
        for (int t = 0; t < 8; ++t) xa[t] = xin[(size_t)(cc + 16 + t) * NPIX];
      }
#pragma unroll
      for (int u = 0; u < 16; ++u) {
#pragma unroll
        for (int t = 0; t < 8; ++t)
          acc[u] = fmaf(Wv[(g16 + u) * 64 + cc + 8 + t], xb[t], acc[u]);
      }
    }
#pragma unroll
    for (int u = 0; u < 16; ++u) lds[u][lane] = bf16b(acc[u]);
    __syncthreads();
    s16x8* vout = (s16x8*)vbf + (size_t)b * 288 * 256;
#pragma unroll
    for (int r = 0; r < 2; ++r) {
      const int v = r * 64 + lane;          // 0..127
      const int blk_l = v >> 6, ks = (v >> 5) & 1, s = (v >> 4) & 1, c = v & 15;
      s16x8 vv;
#pragma unroll
      for (int t = 0; t < 8; ++t)
        vv[t] = lds[c][blk_l * 32 + ks * 16 + s * 4 + (t & 3) + 8 * (t >> 2)];
      vout[((size_t)(tile * 2 + blk_l)) * 256 + (ks * 2 + s) * 64 + g16 + c] = vv;
    }
  } else {
    const float* W = (g == 4) ? Wq : Wk;
    const float* bias = (g == 4) ? bq : bk;
    float acc[8];
#pragma unroll
    for (int u = 0; u < 8; ++u) acc[u] = bias[u];
#pragma unroll
    for (int cc = 0; cc < 64; cc += 16) {
#pragma unroll
      for (int t = 0; t < 8; ++t) xb[t] = xin[(size_t)(cc + 8 + t) * NPIX];
#pragma unroll
      for (int u = 0; u < 8; ++u) {
#pragma unroll
        for (int t = 0; t < 8; ++t)
          acc[u] = fmaf(W[u * 64 + cc + t], xa[t], acc[u]);
      }
      if (cc + 16 < 64) {
#pragma unroll
        for (int t = 0; t < 8; ++t) xa[t] = xin[(size_t)(cc + 16 + t) * NPIX];
      }
#pragma unroll
      for (int u = 0; u < 8; ++u) {
#pragma unroll
        for (int t = 0; t < 8; ++t)
          acc[u] = fmaf(W[u * 64 + cc + 8 + t], xb[t], acc[u]);
      }
    }
    if (g == 4) {
#pragma unroll
      for (int u = 0; u < 8; ++u) acc[u] *= LOG2E;
    }
    s16x8 p;
#pragma unroll
    for (int u = 0; u < 8; ++u) p[u] = bf16b(acc[u]);
    short* dst = (g == 4) ? qbf : kbf;
    ((s16x8*)dst)[(size_t)b * NPIX + j] = p;
  }
}

// ---------------- Stage 2: flash attention, 32x32x16.  (r13 body; r23:
// 6-wave blocks x 192 j, JBA=48 -> grid 768 = EXACTLY 3 blocks/CU, removing
// the 2-vs-3 block quantization tail of the 576-block grid. Compute body,
// chunking (NCH=9 x 128 i), LDS layout and den path byte-identical.)
// Wave owns ONE 32-j tile (jbase = jb*192 + wid*32), full 64-c accumulation.
// V + q staged via global_load_lds (wave w takes V-slots {w, w+6, w+12<16}),
// double buffered, one barrier per chunk; all 6 waves share the staged V.
// numws (bf16 pairs, native fragment layout, verified r10):
//   addr = ((icb*48+jb)*6+wid)*1024 + u*64 + lane  (uint)
//   with jj=j&31: u = (jj>>3)*2 + ((jj>>1)&1) + 8*(c>>5);
//   lane = ((jj>>2)&1)*32 + (c&31); pair = (j even -> lo16, j odd -> hi16).
template <int NCH>   // NCH = number of 128-i chunks per ic
__global__ __launch_bounds__(384) void attn_kernel(
    const short* __restrict__ qbf, const short* __restrict__ kbf,
    const short* __restrict__ vbf,
    unsigned* __restrict__ numws, float* __restrict__ denws)
{
  __shared__ s16x8 lv[2][1024];   // 32 KB: per chunk 4 units x [ks2][s2][c64]
  __shared__ s16x8 lq[2][128];    // 4 KB: 128 q rows (16B each)

  const int bid = blockIdx.x;
  const int jb = bid % JBA;
  const int rest = bid / JBA;
  const int b = rest % NB;
  const int ic = rest / NB;
  const int tid = threadIdx.x;        // 0..383
  const int wid = tid >> 6, lane = tid & 63;   // wid 0..5
  const int l31 = lane & 31, hi = lane >> 5;
  const int jbase = jb * 192 + wid * 32;
  const int ibase = ic * (NCH * 128);

  const s16x8* q8 = (const s16x8*)qbf + (size_t)b * NPIX;
  const short* krow = kbf + (size_t)b * NPIX * 8;
  const s16x8* v8 = (const s16x8*)vbf + (size_t)b * 288 * 256;

  const f32x16 z16 = {0.f};

  // Score B-operand (wave-fixed): lane (j=l31, s=hi): elems 0-3 =
  // k[jbase+l31][4hi..4hi+3], elems 4-7 = ZERO (k>=8 of the K=16 MFMA).
  s16x8 kf;
  {
    const s16x4 ka = *(const s16x4*)(krow + (size_t)(jbase + l31) * 8 + hi * 4);
    kf[0] = ka[0]; kf[1] = ka[1]; kf[2] = ka[2]; kf[3] = ka[3];
    kf[4] = 0; kf[5] = 0; kf[6] = 0; kf[7] = 0;
  }

  f32x16 acc0 = z16, acc1 = z16;
  f32x2 dA = {0.f, 0.f};
  const int vl = hi * 64 + l31;

  // V chunk = 16 wave-load slots of 64 s16x8 entries each; 6 waves cover
  // {w, w+6, w+12(<16)}. q = 128 rows = 2 slots on waves 0,1.
  auto stage = [&](int ch, int bf) {
    const size_t ebase = ((size_t)(ibase >> 5) + ch * 4) * 256;  // s16x8 entries
    gload_lds16(&v8[ebase + wid * 64 + lane], &lv[bf][wid * 64]);
    gload_lds16(&v8[ebase + (wid + 6) * 64 + lane], &lv[bf][(wid + 6) * 64]);
    if (wid < 4)
      gload_lds16(&v8[ebase + (wid + 12) * 64 + lane], &lv[bf][(wid + 12) * 64]);
    if (wid < 2)
      gload_lds16(&q8[(size_t)ibase + ch * 128 + wid * 64 + lane], &lq[bf][wid * 64]);
  };

  stage(0, 0);
  __syncthreads();           // drains vmcnt(0): buf0 staged

  int buf = 0;
  for (int ch = 0; ch < NCH; ++ch) {
    if (ch + 1 < NCH) stage(ch + 1, buf ^ 1);   // loads fly under compute
#pragma unroll
    for (int u = 0; u < 4; ++u) {
      const s16x4 qh = *(const s16x4*)((const short*)&lq[buf][0] + (u * 32 + l31) * 8 + hi * 4);
      s16x8 af;
      af[0] = qh[0]; af[1] = qh[1]; af[2] = qh[2]; af[3] = qh[3];
      af[4] = 0; af[5] = 0; af[6] = 0; af[7] = 0;
      const s16x8 vf00 = lv[buf][u * 256 + vl];          // ks0, c 0-31
      const s16x8 vf01 = lv[buf][u * 256 + 32 + vl];     // ks0, c 32-63
      const s16x8 vf10 = lv[buf][u * 256 + 128 + vl];    // ks1, c 0-31
      const s16x8 vf11 = lv[buf][u * 256 + 160 + vl];    // ks1, c 32-63

      const f32x16 S = __builtin_amdgcn_mfma_f32_32x32x16_bf16(af, kf, z16, 0, 0, 0);
      const float e0 = EXP2(S[0]),  e1 = EXP2(S[1]),  e2 = EXP2(S[2]),  e3 = EXP2(S[3]);
      const float e4 = EXP2(S[4]),  e5 = EXP2(S[5]),  e6 = EXP2(S[6]),  e7 = EXP2(S[7]);
      const float e8 = EXP2(S[8]),  e9 = EXP2(S[9]),  eA = EXP2(S[10]), eB = EXP2(S[11]);
      const float eC = EXP2(S[12]), eD = EXP2(S[13]), eE = EXP2(S[14]), eF = EXP2(S[15]);
      dA += (f32x2){e0, e1}; dA += (f32x2){e2, e3};
      dA += (f32x2){e4, e5}; dA += (f32x2){e6, e7};
      dA += (f32x2){e8, e9}; dA += (f32x2){eA, eB};
      dA += (f32x2){eC, eD}; dA += (f32x2){eE, eF};
      int4 p0i, p1i;
      p0i.x = cvtpk(e0, e1); p0i.y = cvtpk(e2, e3);
      p0i.z = cvtpk(e4, e5); p0i.w = cvtpk(e6, e7);
      p1i.x = cvtpk(e8, e9); p1i.y = cvtpk(eA, eB);
      p1i.z = cvtpk(eC, eD); p1i.w = cvtpk(eE, eF);
      const s16x8 A0 = __builtin_bit_cast(s16x8, p0i);   // i 0..15 of unit
      const s16x8 A1 = __builtin_bit_cast(s16x8, p1i);   // i 16..31
      acc0 = __builtin_amdgcn_mfma_f32_32x32x16_bf16(A0, vf00, acc0, 0, 0, 0);
      acc1 = __builtin_amdgcn_mfma_f32_32x32x16_bf16(A0, vf01, acc1, 0, 0, 0);
      acc0 = __builtin_amdgcn_mfma_f32_32x32x16_bf16(A1, vf10, acc0, 0, 0, 0);
      acc1 = __builtin_amdgcn_mfma_f32_32x32x16_bf16(A1, vf11, acc1, 0, 0, 0);
    }
    __syncthreads();         // all reads of buf done; next-stage loads drained
    buf ^= 1;
  }

  // den: lanes l and l^32 hold complementary i-subsets of the same j.
  float den = dA[0] + dA[1];
  den += __shfl_xor(den, 32);
  const size_t icb = (size_t)ic * NB + b;
  if (lane < 32) denws[icb * NPIX + jbase + l31] = den;

  // Tail: 16 coalesced uint stores in native fragment layout.
  const size_t wavebase = (((size_t)icb * JBA + jb) * 6 + wid) * 1024;
#pragma unroll
  for (int qd = 0; qd < 4; ++qd) {
    numws[wavebase + (qd * 2 + 0) * 64 + lane] = cvtpk(acc0[4 * qd + 0], acc0[4 * qd + 1]);
    numws[wavebase + (qd * 2 + 1) * 64 + lane] = cvtpk(acc0[4 * qd + 2], acc0[4 * qd + 3]);
    numws[wavebase + (8 + qd * 2 + 0) * 64 + lane] = cvtpk(acc1[4 * qd + 0], acc1[4 * qd + 1]);
    numws[wavebase + (8 + qd * 2 + 1) * 64 + lane] = cvtpk(acc1[4 * qd + 2], acc1[4 * qd + 3]);
  }
}

// ---------------- Stage 3: combine i-splits, normalize, add residual.
// Decode verified in r10 (adapted to JBA=48/6-wave): for output (c, j):
//   jt = j>>5 (32-j tile in [0,288)); jb = jt/6; wid = jt%6; jj = j&31:
//   u = (jj>>3)*2 + ((jj>>1)&1) + 8*(c>>5);
//   lane = ((jj>>2)&1)*32 + (c&31); pair sel = j&1 (even->lo16, odd->hi16).
template <int NIC>
__global__ __launch_bounds__(256) void combine_kernel(
    const float* __restrict__ bev, const unsigned* __restrict__ numws,
    const float* __restrict__ denws, float* __restrict__ out)
{
  const int tid = threadIdx.x;
  const int m = tid & 15;          // j-pair within the 32-j tile: jj = 2m, 2m+1
  const int q = tid >> 4;          // c-quad: c = 4q .. 4q+3
  const int b = blockIdx.y;
  const int j0 = blockIdx.x * 32 + 2 * m;       // even j
  const int jt = j0 >> 5;
  const int jb = jt / 6, wid = jt % 6;
  const int u = (m >> 2) * 2 + (m & 1) + 8 * (q >> 3);
  const int laneoff = ((m >> 1) & 1) * 32 + 4 * (q & 7);

  float n0[4] = {0.f, 0.f, 0.f, 0.f}, n1[4] = {0.f, 0.f, 0.f, 0.f};
  float d0 = 0.f, d1 = 0.f;
#pragma unroll
  for (int ic = 0; ic < NIC; ++ic) {
    const size_t icb = (size_t)ic * NB + b;
    const size_t base = (((icb * JBA + jb) * 6 + wid) * 1024) + u * 64 + laneoff;
    const uint4 un = *(const uint4*)&numws[base];
    n0[0] += __builtin_bit_cast(float, un.x << 16);
    n1[0] += __builtin_bit_cast(float, un.x & 0xFFFF0000u);
    n0[1] += __builtin_bit_cast(float, un.y << 16);
    n1[1] += __builtin_bit_cast(float, un.y & 0xFFFF0000u);
    n0[2] += __builtin_bit_cast(float, un.z << 16);
    n1[2] += __builtin_bit_cast(float, un.z & 0xFFFF0000u);
    n0[3] += __builtin_bit_cast(float, un.w << 16);
    n1[3] += __builtin_bit_cast(float, un.w & 0xFFFF0000u);
    const float2 dd = *(const float2*)&denws[icb * NPIX + j0];
    d0 += dd.x; d1 += dd.y;
  }
  const float r0 = 1.f / d0, r1 = 1.f / d1;
#pragma unroll
  for (int e = 0; e < 4; ++e) {
    const int c = 4 * q + e;
    const size_t o = ((size_t)b * NC + c) * NPIX + j0;
    float2 z2;
    z2.x = bev[o] + n0[e] * r0;
    z2.y = bev[o + 1] + n1[e] * r1;
    *(float2*)&out[o] = z2;
  }
}

extern "C" void kernel_launch(void* const* d_in, const int* in_sizes, int n_in,
                              void* d_out, int out_size, void* d_ws, size_t ws_size,
                              hipStream_t stream) {
  const float* rv  = (const float*)d_in[0];
  const float* bev = (const float*)d_in[1];
  const float* Wq  = (const float*)d_in[2];
  const float* bq  = (const float*)d_in[3];
  const float* Wk  = (const float*)d_in[4];
  const float* bk  = (const float*)d_in[5];
  const float* Wv  = (const float*)d_in[6];
  const float* bv  = (const float*)d_in[7];
  float* out = (float*)d_out;

  short* qbf = (short*)d_ws;
  short* kbf = qbf + (size_t)NB * NPIX * 8;
  short* vbf = kbf + (size_t)NB * NPIX * 8;
  float* denws = (float*)(vbf + (size_t)NB * NPIX * 64);

  const size_t fixed = (size_t)NB * NPIX * (8 + 8 + 64) * 2;  // qkv bytes
  int nic = 8;
  while (nic > 2) {
    size_t need = fixed + (size_t)nic * NB * NPIX * 4                // denws
                        + (size_t)nic * NB * JBA * 6 * 1024 * 4;     // numws
    if (need <= ws_size) break;
    nic >>= 1;
  }
  unsigned* numws = (unsigned*)(denws + (size_t)nic * NB * NPIX);

  cvt_qkv_kernel<<<dim3(288, 6, NB), 64, 0, stream>>>(
      rv, bev, Wq, bq, Wk, bk, Wv, bv, qbf, kbf, vbf);
  const int nblk = nic * NB * JBA;
  if (nic == 8) {
    attn_kernel<9><<<dim3(nblk), 384, 0, stream>>>(qbf, kbf, vbf, numws, denws);
    combine_kernel<8><<<dim3(288, NB), 256, 0, stream>>>(bev, numws, denws, out);
  } else if (nic == 4) {
    attn_kernel<18><<<dim3(nblk), 384, 0, stream>>>(qbf, kbf, vbf, numws, denws);
    combine_kernel<4><<<dim3(288, NB), 256, 0, stream>>>(bev, numws, denws, out);
  } else {
    attn_kernel<36><<<dim3(nblk), 384, 0, stream>>>(qbf, kbf, vbf, numws, denws);
    combine_kernel<2><<<dim3(288, NB), 256, 0, stream>>>(bev, numws, denws, out);
  }
}